// Round 6
// baseline (875.728 us; speedup 1.0000x reference)
//
#include <hip/hip_runtime.h>

// ComplexWindowAttn: B=2048 windows, DIM=96, HEADS=6, HEAD_DIM=16, N=64 (8x8).
// Fully fused: qkv cGEMM -> per-head complex attention w/ magnitude-softmax
// renormalization -> proj cGEMM. One block per window, fp32 vector math.
//
// R5 post-mortem: real-plane output layout CONFIRMED (absmax 0.672->1.123e-2,
// just over the 1.094e-2 threshold). Residual error == bf16 x-staging tail.
// R6: drop the bf16 LDS staging of x entirely; read x fp32 straight from
// global (coalesced, L2-resident across the 6 head passes; ~590 MB L2 traffic
// ~ 17us, noise vs ~330us fp32 compute floor). LDS now 32 KB -> 4 blocks/CU.
//
// Static LDS (32 KB):
//   qs   [16][64] fp32 complex = 8192 B   (q pre-scaled by 0.25)
//   ks   [16][64] fp32 complex = 8192 B
//   vs   [16][64] fp32 complex = 8192 B
//   outh [16][64] fp32 complex = 8192 B

#define HEADS 6
#define BLOCK 512
#define SCALE 0.25f

__global__ __launch_bounds__(BLOCK) void cwattn_kernel(
    const float* __restrict__ x_real, const float* __restrict__ x_imag,
    const float* __restrict__ qkv_wr, const float* __restrict__ qkv_wi,
    const float* __restrict__ proj_wr, const float* __restrict__ proj_wi,
    const float* __restrict__ rel, float* __restrict__ out,
    long long out_elems)
{
    __shared__ float2 qs[16 * 64];
    __shared__ float2 ks[16 * 64];
    __shared__ float2 vs[16 * 64];
    __shared__ float2 outh[16 * 64];

    const int b    = blockIdx.x;
    const int t    = threadIdx.x;
    const int lane = t & 63;
    const int wave = __builtin_amdgcn_readfirstlane(t >> 6);  // 0..7, SGPR

    const float* xr = x_real + (size_t)b * 6144;  // 96*64, [c][n]
    const float* xi = x_imag + (size_t)b * 6144;

    // ---- persistent proj accumulators: rows o = wave*12 + j, col n = lane ----
    float yr[12], yi[12];
#pragma unroll
    for (int j = 0; j < 12; ++j) { yr[j] = 0.f; yi[j] = 0.f; }

    // score-phase thread mapping: row n = g (0..63), m-chunk mo (0..7)
    const int g  = t >> 3;
    const int mo = t & 7;
    const int m0 = mo * 8;
    const int gi = g >> 3, gj = g & 7;

    for (int h = 0; h < HEADS; ++h) {
        // ================= qkv tiles: 48 rows (16 q + 16 k + 16 v), 6/wave ==
        {
            float ar[6], ai[6];
#pragma unroll
            for (int j = 0; j < 6; ++j) { ar[j] = 0.f; ai[j] = 0.f; }
            const int r0 = wave * 6;
            const float* wrp[6]; const float* wip[6];
#pragma unroll
            for (int j = 0; j < 6; ++j) {
                int r = r0 + j;
                int s = r >> 4;                 // 0=q,1=k,2=v
                int o = s * 96 + h * 16 + (r & 15);
                wrp[j] = qkv_wr + o * 96;
                wip[j] = qkv_wi + o * 96;
            }
#pragma unroll 4
            for (int c = 0; c < 96; ++c) {
                float xre = xr[c * 64 + lane];   // coalesced, L2-hot after h=0
                float xim = xi[c * 64 + lane];
#pragma unroll
                for (int j = 0; j < 6; ++j) {
                    float wr = wrp[j][c], wi = wip[j][c];
                    ar[j] = fmaf(wr, xre, fmaf(-wi, xim, ar[j]));
                    ai[j] = fmaf(wr, xim, fmaf( wi, xre, ai[j]));
                }
            }
#pragma unroll
            for (int j = 0; j < 6; ++j) {
                int r  = r0 + j;
                int s  = r >> 4;
                int rd = r & 15;
                float scl   = (s == 0) ? SCALE : 1.0f;
                float2* dst = (s == 0) ? qs : ((s == 1) ? ks : vs);
                dst[rd * 64 + lane] = make_float2(ar[j] * scl, ai[j] * scl);
            }
        }
        __syncthreads();

        // ================= scores + magnitude-softmax + PV =================
        {
            float sr[8], si[8];
#pragma unroll
            for (int j = 0; j < 8; ++j) { sr[j] = 0.f; si[j] = 0.f; }
            for (int d = 0; d < 16; ++d) {
                float2 q2 = qs[d * 64 + g];
#pragma unroll
                for (int j = 0; j < 8; ++j) {
                    float2 k2 = ks[d * 64 + m0 + j];
                    // q * conj(k)
                    sr[j] = fmaf(q2.x, k2.x, fmaf( q2.y, k2.y, sr[j]));
                    si[j] = fmaf(q2.y, k2.x, fmaf(-q2.x, k2.y, si[j]));
                }
            }
            const float* relh = rel + h * 225;
            float mag[8], e[8];
            float mx = -1e30f;
#pragma unroll
            for (int j = 0; j < 8; ++j) {
                int m = m0 + j;
                int idx = (gi - (m >> 3) + 7) * 15 + (gj - (m & 7) + 7);
                sr[j] += relh[idx];                      // bias is real
                mag[j] = sqrtf(fmaf(sr[j], sr[j], si[j] * si[j]));
                mx = fmaxf(mx, mag[j]);
            }
            mx = fmaxf(mx, __shfl_xor(mx, 1));
            mx = fmaxf(mx, __shfl_xor(mx, 2));
            mx = fmaxf(mx, __shfl_xor(mx, 4));
            float ssum = 0.f;
#pragma unroll
            for (int j = 0; j < 8; ++j) { e[j] = __expf(mag[j] - mx); ssum += e[j]; }
            ssum += __shfl_xor(ssum, 1);
            ssum += __shfl_xor(ssum, 2);
            ssum += __shfl_xor(ssum, 4);
            float isum = 1.0f / ssum;
#pragma unroll
            for (int j = 0; j < 8; ++j) {
                float f = e[j] * isum / (mag[j] + 1e-8f);
                sr[j] *= f; si[j] *= f;
            }
            // PV: out[d][n] = sum_m attn[n][m] * v[d][m]
            for (int d = 0; d < 16; ++d) {
                float pr = 0.f, pi = 0.f;
#pragma unroll
                for (int j = 0; j < 8; ++j) {
                    float2 v2 = vs[d * 64 + m0 + j];
                    pr = fmaf(sr[j], v2.x, fmaf(-si[j], v2.y, pr));
                    pi = fmaf(sr[j], v2.y, fmaf( si[j], v2.x, pi));
                }
                pr += __shfl_xor(pr, 1); pr += __shfl_xor(pr, 2); pr += __shfl_xor(pr, 4);
                pi += __shfl_xor(pi, 1); pi += __shfl_xor(pi, 2); pi += __shfl_xor(pi, 4);
                if (mo == 0) outh[d * 64 + g] = make_float2(pr, pi);
            }
        }
        __syncthreads();

        // ================= proj: accumulate this head's contribution =======
        {
            const float* pr0 = proj_wr + (wave * 12) * 96 + h * 16;
            const float* pi0 = proj_wi + (wave * 12) * 96 + h * 16;
            for (int d = 0; d < 16; ++d) {
                float2 o2 = outh[d * 64 + lane];
#pragma unroll
                for (int j = 0; j < 12; ++j) {
                    float wr = pr0[j * 96 + d];
                    float wi = pi0[j * 96 + d];
                    yr[j] = fmaf(wr, o2.x, fmaf(-wi, o2.y, yr[j]));
                    yi[j] = fmaf(wr, o2.y, fmaf( wi, o2.x, yi[j]));
                }
            }
        }
        __syncthreads();
    }

    // ---- write y: real plane at [0, B*6144), imag plane (if room) at
    //      [B*6144, 2*B*6144). Each store bounds-checked vs out_elems. ----
    const long long n_total = (long long)gridDim.x * 6144;
#pragma unroll
    for (int j = 0; j < 12; ++j) {
        int o = wave * 12 + j;
        long long ci = (long long)b * 6144 + o * 64 + lane;
        if (ci < out_elems)           out[ci]           = yr[j];
        if (n_total + ci < out_elems) out[n_total + ci] = yi[j];
    }
}

extern "C" void kernel_launch(void* const* d_in, const int* in_sizes, int n_in,
                              void* d_out, int out_size, void* d_ws, size_t ws_size,
                              hipStream_t stream) {
    const float* x_real  = (const float*)d_in[0];
    const float* x_imag  = (const float*)d_in[1];
    const float* qkv_wr  = (const float*)d_in[2];
    const float* qkv_wi  = (const float*)d_in[3];
    const float* proj_wr = (const float*)d_in[4];
    const float* proj_wi = (const float*)d_in[5];
    const float* rel     = (const float*)d_in[6];
    float* out = (float*)d_out;

    const int B = in_sizes[0] / 6144;   // 96*64 per window
    cwattn_kernel<<<B, BLOCK, 0, stream>>>(
        x_real, x_imag, qkv_wr, qkv_wi, proj_wr, proj_wi, rel, out,
        (long long)out_size);
}

// Round 7
// 565.339 us; speedup vs baseline: 1.5490x; 1.5490x over previous
//
#include <hip/hip_runtime.h>
#include <hip/hip_fp16.h>

// ComplexWindowAttn: B=2048 windows, DIM=96, HEADS=6, HEAD_DIM=16, N=64 (8x8).
// R7: staged MFMA conversion.
//   K1: qkv weights fp32 -> f16 planes (wr, wi, -wi) in d_ws.
//   K2: per-window qkv cGEMM on mfma_f32_16x16x32_f16; x^T staged in LDS as
//       f16 (B^T layout, m92 pattern); outputs packed (half re, half im) u32
//       into d_ws workspace [b][288][64].
//   K3: round-6 verified attention+proj, loading q/k/v from workspace;
//       proj computes REAL part only (output confirmed real-plane, R6).
// Fallback: if ws_size too small, run the verified round-6 fused kernel.

#define HEADS 6
#define BLOCK 512
#define SCALE 0.25f

typedef _Float16 f16x8 __attribute__((ext_vector_type(8)));
typedef float    f32x4 __attribute__((ext_vector_type(4)));

#define WQ_ELEMS   27648              // 288*96 per plane
#define WS_WQ_B    165888             // 3 planes * 27648 * 2B
#define XT_PITCH   104                // 96 + 8 pad (keeps 16B alignment)

// ===================== K1: weight conversion =====================
__global__ void prep_w_kernel(const float* __restrict__ wr,
                              const float* __restrict__ wi,
                              __half* __restrict__ wq)
{
    int i = blockIdx.x * 256 + threadIdx.x;
    if (i < WQ_ELEMS) {
        wq[i]                 = __float2half(wr[i]);
        wq[WQ_ELEMS + i]      = __float2half(wi[i]);
        wq[2 * WQ_ELEMS + i]  = __float2half(-wi[i]);
    }
}

// ===================== K2: qkv complex GEMM via MFMA =====================
// Per window: C[288][64] = W(288x96) * x(96x64), complex.
// C_r = Wr*xr + (-Wi)*xi ; C_i = Wr*xi + Wi*xr.
__global__ __launch_bounds__(BLOCK) void qkv_mfma_kernel(
    const float* __restrict__ x_real, const float* __restrict__ x_imag,
    const __half* __restrict__ wq, unsigned* __restrict__ qkvp)
{
    __shared__ __align__(16) _Float16 xtr_r[64 * XT_PITCH];
    __shared__ __align__(16) _Float16 xtr_i[64 * XT_PITCH];

    const int b = blockIdx.x, t = threadIdx.x;
    const float* xr = x_real + (size_t)b * 6144;   // [c][n]
    const float* xi = x_imag + (size_t)b * 6144;

    // stage x^T (B^T layout: row n, contiguous c) as f16
    for (int i = t; i < 6144; i += BLOCK) {
        int c = i >> 6, n = i & 63;
        xtr_r[n * XT_PITCH + c] = (_Float16)xr[i];
        xtr_i[n * XT_PITCH + c] = (_Float16)xi[i];
    }
    __syncthreads();

    const int w    = __builtin_amdgcn_readfirstlane(t >> 6);
    const int lane = t & 63;
    const int l16  = lane & 15;       // A: row m; C: col n
    const int quad = lane >> 4;       // A/B: k-group; C: row-group

    const __half* wr_p  = wq;
    const __half* wi_p  = wq + WQ_ELEMS;
    const __half* wni_p = wq + 2 * WQ_ELEMS;
    unsigned* dst = qkvp + (size_t)b * 288 * 64;

    // Mtile assignment: 18 tiles over 8 waves (waves 0,1 take a 3rd tile)
    int mts[3]; int nmt = 2;
    mts[0] = w * 2; mts[1] = w * 2 + 1;
    if (w < 2) { mts[2] = 16 + w; nmt = 3; }

    for (int mi = 0; mi < nmt; ++mi) {
        const int mt = mts[mi];
        f16x8 a_r[3], a_i[3], a_ni[3];
#pragma unroll
        for (int ks = 0; ks < 3; ++ks) {
            size_t off = (size_t)(mt * 16 + l16) * 96 + ks * 32 + quad * 8;
            a_r[ks]  = *reinterpret_cast<const f16x8*>(wr_p  + off);
            a_i[ks]  = *reinterpret_cast<const f16x8*>(wi_p  + off);
            a_ni[ks] = *reinterpret_cast<const f16x8*>(wni_p + off);
        }
#pragma unroll
        for (int nt = 0; nt < 4; ++nt) {
            const int n0 = nt * 16;
            f16x8 b_r[3], b_i[3];
#pragma unroll
            for (int ks = 0; ks < 3; ++ks) {
                int addr = (n0 + l16) * XT_PITCH + ks * 32 + quad * 8;
                b_r[ks] = *reinterpret_cast<const f16x8*>(&xtr_r[addr]);
                b_i[ks] = *reinterpret_cast<const f16x8*>(&xtr_i[addr]);
            }
            f32x4 accr = {0.f, 0.f, 0.f, 0.f};
            f32x4 acci = {0.f, 0.f, 0.f, 0.f};
#pragma unroll
            for (int ks = 0; ks < 3; ++ks) {
                accr = __builtin_amdgcn_mfma_f32_16x16x32_f16(a_r[ks],  b_r[ks], accr, 0, 0, 0);
                accr = __builtin_amdgcn_mfma_f32_16x16x32_f16(a_ni[ks], b_i[ks], accr, 0, 0, 0);
                acci = __builtin_amdgcn_mfma_f32_16x16x32_f16(a_r[ks],  b_i[ks], acci, 0, 0, 0);
                acci = __builtin_amdgcn_mfma_f32_16x16x32_f16(a_i[ks],  b_r[ks], acci, 0, 0, 0);
            }
            // C layout: col = lane&15, row = quad*4 + reg (m89-verified)
#pragma unroll
            for (int r = 0; r < 4; ++r) {
                int o = mt * 16 + quad * 4 + r;
                int n = n0 + l16;
                __half2 p = __floats2half2_rn(accr[r], acci[r]);
                dst[(size_t)o * 64 + n] = *reinterpret_cast<unsigned*>(&p);
            }
        }
    }
}

// ===================== K3: attention + real-part proj =====================
__global__ __launch_bounds__(BLOCK) void attn_proj_kernel(
    const unsigned* __restrict__ qkvp,
    const float* __restrict__ proj_wr, const float* __restrict__ proj_wi,
    const float* __restrict__ rel, float* __restrict__ out)
{
    __shared__ float2 qs[16 * 64];
    __shared__ float2 ks[16 * 64];
    __shared__ float2 vs[16 * 64];
    __shared__ float2 outh[16 * 64];

    const int b    = blockIdx.x;
    const int t    = threadIdx.x;
    const int lane = t & 63;
    const int wave = __builtin_amdgcn_readfirstlane(t >> 6);

    const unsigned* src = qkvp + (size_t)b * 288 * 64;

    float yr[12];
#pragma unroll
    for (int j = 0; j < 12; ++j) yr[j] = 0.f;

    const int g  = t >> 3;
    const int mo = t & 7;
    const int m0 = mo * 8;
    const int gi = g >> 3, gj = g & 7;

    for (int h = 0; h < HEADS; ++h) {
        // ---- load q,k,v from packed workspace ----
        for (int i = t; i < 1024; i += BLOCK) {
            unsigned uq = src[(h * 16) * 64 + i];          // rows h*16+d
            unsigned uk = src[(96 + h * 16) * 64 + i];
            unsigned uv = src[(192 + h * 16) * 64 + i];
            float2 fq = __half22float2(*reinterpret_cast<__half2*>(&uq));
            float2 fk = __half22float2(*reinterpret_cast<__half2*>(&uk));
            float2 fv = __half22float2(*reinterpret_cast<__half2*>(&uv));
            qs[i] = make_float2(fq.x * SCALE, fq.y * SCALE);
            ks[i] = fk;
            vs[i] = fv;
        }
        __syncthreads();

        // ---- scores + magnitude-softmax + PV (verified R6 code) ----
        {
            float sr[8], si[8];
#pragma unroll
            for (int j = 0; j < 8; ++j) { sr[j] = 0.f; si[j] = 0.f; }
            for (int d = 0; d < 16; ++d) {
                float2 q2 = qs[d * 64 + g];
#pragma unroll
                for (int j = 0; j < 8; ++j) {
                    float2 k2 = ks[d * 64 + m0 + j];
                    sr[j] = fmaf(q2.x, k2.x, fmaf( q2.y, k2.y, sr[j]));
                    si[j] = fmaf(q2.y, k2.x, fmaf(-q2.x, k2.y, si[j]));
                }
            }
            const float* relh = rel + h * 225;
            float mag[8], e[8];
            float mx = -1e30f;
#pragma unroll
            for (int j = 0; j < 8; ++j) {
                int m = m0 + j;
                int idx = (gi - (m >> 3) + 7) * 15 + (gj - (m & 7) + 7);
                sr[j] += relh[idx];
                mag[j] = sqrtf(fmaf(sr[j], sr[j], si[j] * si[j]));
                mx = fmaxf(mx, mag[j]);
            }
            mx = fmaxf(mx, __shfl_xor(mx, 1));
            mx = fmaxf(mx, __shfl_xor(mx, 2));
            mx = fmaxf(mx, __shfl_xor(mx, 4));
            float ssum = 0.f;
#pragma unroll
            for (int j = 0; j < 8; ++j) { e[j] = __expf(mag[j] - mx); ssum += e[j]; }
            ssum += __shfl_xor(ssum, 1);
            ssum += __shfl_xor(ssum, 2);
            ssum += __shfl_xor(ssum, 4);
            float isum = 1.0f / ssum;
#pragma unroll
            for (int j = 0; j < 8; ++j) {
                float f = e[j] * isum / (mag[j] + 1e-8f);
                sr[j] *= f; si[j] *= f;
            }
            for (int d = 0; d < 16; ++d) {
                float pr = 0.f, pi = 0.f;
#pragma unroll
                for (int j = 0; j < 8; ++j) {
                    float2 v2 = vs[d * 64 + m0 + j];
                    pr = fmaf(sr[j], v2.x, fmaf(-si[j], v2.y, pr));
                    pi = fmaf(sr[j], v2.y, fmaf( si[j], v2.x, pi));
                }
                pr += __shfl_xor(pr, 1); pr += __shfl_xor(pr, 2); pr += __shfl_xor(pr, 4);
                pi += __shfl_xor(pi, 1); pi += __shfl_xor(pi, 2); pi += __shfl_xor(pi, 4);
                if (mo == 0) outh[d * 64 + g] = make_float2(pr, pi);
            }
        }
        __syncthreads();

        // ---- proj: REAL part only (output is real-plane, R6-confirmed) ----
        {
            const float* pr0 = proj_wr + (wave * 12) * 96 + h * 16;
            const float* pi0 = proj_wi + (wave * 12) * 96 + h * 16;
            for (int d = 0; d < 16; ++d) {
                float2 o2 = outh[d * 64 + lane];
#pragma unroll
                for (int j = 0; j < 12; ++j) {
                    float wr = pr0[j * 96 + d];
                    float wi = pi0[j * 96 + d];
                    yr[j] = fmaf(wr, o2.x, fmaf(-wi, o2.y, yr[j]));
                }
            }
        }
        __syncthreads();
    }

#pragma unroll
    for (int j = 0; j < 12; ++j) {
        int o = wave * 12 + j;
        out[(size_t)b * 6144 + o * 64 + lane] = yr[j];
    }
}

// ===================== Fallback: verified R6 fused kernel =====================
__global__ __launch_bounds__(BLOCK) void cwattn_kernel(
    const float* __restrict__ x_real, const float* __restrict__ x_imag,
    const float* __restrict__ qkv_wr, const float* __restrict__ qkv_wi,
    const float* __restrict__ proj_wr, const float* __restrict__ proj_wi,
    const float* __restrict__ rel, float* __restrict__ out,
    long long out_elems)
{
    __shared__ float2 qs[16 * 64];
    __shared__ float2 ks[16 * 64];
    __shared__ float2 vs[16 * 64];
    __shared__ float2 outh[16 * 64];

    const int b    = blockIdx.x;
    const int t    = threadIdx.x;
    const int lane = t & 63;
    const int wave = __builtin_amdgcn_readfirstlane(t >> 6);

    const float* xr = x_real + (size_t)b * 6144;
    const float* xi = x_imag + (size_t)b * 6144;

    float yr[12], yi[12];
#pragma unroll
    for (int j = 0; j < 12; ++j) { yr[j] = 0.f; yi[j] = 0.f; }

    const int g  = t >> 3;
    const int mo = t & 7;
    const int m0 = mo * 8;
    const int gi = g >> 3, gj = g & 7;

    for (int h = 0; h < HEADS; ++h) {
        {
            float ar[6], ai[6];
#pragma unroll
            for (int j = 0; j < 6; ++j) { ar[j] = 0.f; ai[j] = 0.f; }
            const int r0 = wave * 6;
            const float* wrp[6]; const float* wip[6];
#pragma unroll
            for (int j = 0; j < 6; ++j) {
                int r = r0 + j;
                int s = r >> 4;
                int o = s * 96 + h * 16 + (r & 15);
                wrp[j] = qkv_wr + o * 96;
                wip[j] = qkv_wi + o * 96;
            }
#pragma unroll 4
            for (int c = 0; c < 96; ++c) {
                float xre = xr[c * 64 + lane];
                float xim = xi[c * 64 + lane];
#pragma unroll
                for (int j = 0; j < 6; ++j) {
                    float wr = wrp[j][c], wi = wip[j][c];
                    ar[j] = fmaf(wr, xre, fmaf(-wi, xim, ar[j]));
                    ai[j] = fmaf(wr, xim, fmaf( wi, xre, ai[j]));
                }
            }
#pragma unroll
            for (int j = 0; j < 6; ++j) {
                int r  = r0 + j;
                int s  = r >> 4;
                int rd = r & 15;
                float scl   = (s == 0) ? SCALE : 1.0f;
                float2* dst = (s == 0) ? qs : ((s == 1) ? ks : vs);
                dst[rd * 64 + lane] = make_float2(ar[j] * scl, ai[j] * scl);
            }
        }
        __syncthreads();
        {
            float sr[8], si[8];
#pragma unroll
            for (int j = 0; j < 8; ++j) { sr[j] = 0.f; si[j] = 0.f; }
            for (int d = 0; d < 16; ++d) {
                float2 q2 = qs[d * 64 + g];
#pragma unroll
                for (int j = 0; j < 8; ++j) {
                    float2 k2 = ks[d * 64 + m0 + j];
                    sr[j] = fmaf(q2.x, k2.x, fmaf( q2.y, k2.y, sr[j]));
                    si[j] = fmaf(q2.y, k2.x, fmaf(-q2.x, k2.y, si[j]));
                }
            }
            const float* relh = rel + h * 225;
            float mag[8], e[8];
            float mx = -1e30f;
#pragma unroll
            for (int j = 0; j < 8; ++j) {
                int m = m0 + j;
                int idx = (gi - (m >> 3) + 7) * 15 + (gj - (m & 7) + 7);
                sr[j] += relh[idx];
                mag[j] = sqrtf(fmaf(sr[j], sr[j], si[j] * si[j]));
                mx = fmaxf(mx, mag[j]);
            }
            mx = fmaxf(mx, __shfl_xor(mx, 1));
            mx = fmaxf(mx, __shfl_xor(mx, 2));
            mx = fmaxf(mx, __shfl_xor(mx, 4));
            float ssum = 0.f;
#pragma unroll
            for (int j = 0; j < 8; ++j) { e[j] = __expf(mag[j] - mx); ssum += e[j]; }
            ssum += __shfl_xor(ssum, 1);
            ssum += __shfl_xor(ssum, 2);
            ssum += __shfl_xor(ssum, 4);
            float isum = 1.0f / ssum;
#pragma unroll
            for (int j = 0; j < 8; ++j) {
                float f = e[j] * isum / (mag[j] + 1e-8f);
                sr[j] *= f; si[j] *= f;
            }
            for (int d = 0; d < 16; ++d) {
                float pr = 0.f, pi = 0.f;
#pragma unroll
                for (int j = 0; j < 8; ++j) {
                    float2 v2 = vs[d * 64 + m0 + j];
                    pr = fmaf(sr[j], v2.x, fmaf(-si[j], v2.y, pr));
                    pi = fmaf(sr[j], v2.y, fmaf( si[j], v2.x, pi));
                }
                pr += __shfl_xor(pr, 1); pr += __shfl_xor(pr, 2); pr += __shfl_xor(pr, 4);
                pi += __shfl_xor(pi, 1); pi += __shfl_xor(pi, 2); pi += __shfl_xor(pi, 4);
                if (mo == 0) outh[d * 64 + g] = make_float2(pr, pi);
            }
        }
        __syncthreads();
        {
            const float* pr0 = proj_wr + (wave * 12) * 96 + h * 16;
            const float* pi0 = proj_wi + (wave * 12) * 96 + h * 16;
            for (int d = 0; d < 16; ++d) {
                float2 o2 = outh[d * 64 + lane];
#pragma unroll
                for (int j = 0; j < 12; ++j) {
                    float wr = pr0[j * 96 + d];
                    float wi = pi0[j * 96 + d];
                    yr[j] = fmaf(wr, o2.x, fmaf(-wi, o2.y, yr[j]));
                    yi[j] = fmaf(wr, o2.y, fmaf( wi, o2.x, yi[j]));
                }
            }
        }
        __syncthreads();
    }

    const long long n_total = (long long)gridDim.x * 6144;
#pragma unroll
    for (int j = 0; j < 12; ++j) {
        int o = wave * 12 + j;
        long long ci = (long long)b * 6144 + o * 64 + lane;
        if (ci < out_elems)           out[ci]           = yr[j];
        if (n_total + ci < out_elems) out[n_total + ci] = yi[j];
    }
}

// ===================== host =====================
extern "C" void kernel_launch(void* const* d_in, const int* in_sizes, int n_in,
                              void* d_out, int out_size, void* d_ws, size_t ws_size,
                              hipStream_t stream) {
    const float* x_real  = (const float*)d_in[0];
    const float* x_imag  = (const float*)d_in[1];
    const float* qkv_wr  = (const float*)d_in[2];
    const float* qkv_wi  = (const float*)d_in[3];
    const float* proj_wr = (const float*)d_in[4];
    const float* proj_wi = (const float*)d_in[5];
    const float* rel     = (const float*)d_in[6];
    float* out = (float*)d_out;

    const int B = in_sizes[0] / 6144;
    const size_t need = (size_t)WS_WQ_B + (size_t)B * 288 * 64 * 4;

    if (ws_size >= need) {
        __half*   wq   = (__half*)d_ws;
        unsigned* qkvp = (unsigned*)((char*)d_ws + WS_WQ_B);
        prep_w_kernel<<<(WQ_ELEMS + 255) / 256, 256, 0, stream>>>(qkv_wr, qkv_wi, wq);
        qkv_mfma_kernel<<<B, BLOCK, 0, stream>>>(x_real, x_imag, wq, qkvp);
        attn_proj_kernel<<<B, BLOCK, 0, stream>>>(qkvp, proj_wr, proj_wi, rel, out);
    } else {
        cwattn_kernel<<<B, BLOCK, 0, stream>>>(
            x_real, x_imag, qkv_wr, qkv_wi, proj_wr, proj_wi, rel, out,
            (long long)out_size);
    }
}